// Round 7
// baseline (127.217 us; speedup 1.0000x reference)
//
#include <hip/hip_runtime.h>

#define NPTS 8192
#define DIM 64
#define EPSF 1e-7f
#define LN2F 0.69314718055994531f
#define NBLK 1056      // sum_{by=0}^{31} (64 - 2*by)

typedef unsigned short u16;
typedef __attribute__((ext_vector_type(8))) short bf16x8;   // 8 bf16 (4 VGPRs)
typedef __attribute__((ext_vector_type(8))) unsigned short u16x8;
typedef __attribute__((ext_vector_type(4))) float f32x4;
typedef __attribute__((ext_vector_type(2))) float f32x2;

// ---- kernel 1: x -> bf16 (round-to-nearest); meta = {-sq/2, 1/(1-sq), -4/(1-sq), label}
__global__ void prep_kernel(const float* __restrict__ x, const int* __restrict__ labels,
                            u16* __restrict__ hi,
                            float4* __restrict__ meta,
                            float* __restrict__ out) {
    int g = blockIdx.x * blockDim.x + threadIdx.x;   // 0 .. NPTS*8-1
    int row = g >> 3, sub = g & 7;
    const float* xp = x + row * DIM + sub * 8;
    float v[8];
    float s = 0.f;
#pragma unroll
    for (int k = 0; k < 8; k++) { v[k] = xp[k]; s = fmaf(v[k], v[k], s); }
    s += __shfl_xor(s, 1);
    s += __shfl_xor(s, 2);
    s += __shfl_xor(s, 4);
    u16x8 h;
#pragma unroll
    for (int k = 0; k < 8; k++) {
        unsigned int bits = __float_as_uint(v[k]);
        unsigned int r = bits + 0x7FFFu + ((bits >> 16) & 1u);   // RTN-even bf16
        h[k] = (u16)(r >> 16);
    }
    *(u16x8*)(hi + row * DIM + sub * 8) = h;
    if (sub == 0) {
        float r = 1.0f / (1.0f - s);
        meta[row] = make_float4(-0.5f * s, r, -4.0f * r, (float)labels[row]);
    }
    if (g == 3) out[0] = 0.f;
}

// C(b) = number of active tiles with by < b
__device__ __forceinline__ int cumtiles(int b) { return 65 * b - b * b; }

// ---- kernel 2: triangular fused MFMA Gram + hyperbolic epilogue -------------
// R24: STATIC PREFETCH. Evidence: VALU-busy TIME is constant ~14us across all
// variants (R17 14.4 / R19 14.8 / R20 13.4 / R21 14.2) while the wall varies
// 40->64us -> fixed instruction stream + variant-independent stall. The one
// construct every variant shared: a *dynamic* prefetch guard `if (t < N-1)`
// inside the K-loop. Loads inside a conditional make vmcnt uncountable at
// the merge point -> compiler emits s_waitcnt vmcnt(0) before the consumers,
// draining the just-issued t+1 prefetch -> dbuf defeated, full L2 round trip
// every iteration (~1300 cy/iter stall, matching measurement). Fix: FULL
// unroll of the 8-step loop; `if (t<7)` resolves statically, straight-line
// code, compiler can emit counted vmcnt(N) leaving prefetch in flight.
// Base = R22 (4-wave, atomic-free Pi/Pj outputs).
__global__ void __launch_bounds__(256, 4) pair_mfma(
        const u16* __restrict__ hi,
        const float4* __restrict__ meta,
        float* __restrict__ Pi, float* __restrict__ Pj) {
    __shared__ float slabS[4][128], slabT[4][128];

    int tid = threadIdx.x;
    int wave = tid >> 6, lane = tid & 63;
    int quad = lane >> 4, l15 = lane & 15;

    // invert linear tile id -> (by, bx) in the triangular tile set
    int bid2 = blockIdx.x;
    int bid = bid2 >> 1;
    int half = bid2 & 1;
    int by = (int)((65.0f - __builtin_amdgcn_sqrtf(4225.0f - 4.0f * (float)bid)) * 0.5f);
    while (cumtiles(by + 1) <= bid) by++;
    while (cumtiles(by) > bid) by--;
    int off = bid - cumtiles(by);
    int bx = 2 * by + off;
    bool full = (off >= 2);

    int i0 = bx * 128 + wave * 32;
    int j0 = by * 256;
    int jbase = j0 + half * 128;     // this block's 8 j-groups start here

    bf16x8 a_hi[2][2];
#pragma unroll
    for (int it = 0; it < 2; it++)
#pragma unroll
        for (int ks = 0; ks < 2; ks++) {
            int aoff = (i0 + it * 16 + l15) * DIM + ks * 32 + quad * 8;
            a_hi[it][ks] = *(const bf16x8*)(hi + aoff);
        }

    f32x4 hsqi4[2];          // -sq_i/2 for this lane's 8 rows (C-init vector)
    f32x2 rcp2[4];           // 1/(1-sq_i) packed pairs
    float labi[8];
#pragma unroll
    for (int it = 0; it < 2; it++)
#pragma unroll
        for (int r = 0; r < 4; r++) {
            float4 m = meta[i0 + it * 16 + quad * 4 + r];
            hsqi4[it][r] = m.x;
            rcp2[it * 2 + (r >> 1)][r & 1] = m.y;
            labi[it * 4 + r] = m.w;
        }

    if (full) {
        slabS[wave][lane] = 0.f;       slabT[wave][lane] = 0.f;
        slabS[wave][lane + 64] = 0.f;  slabT[wave][lane + 64] = 0.f;
    }

    f32x2 Sx2[4], Tx2[4];
#pragma unroll
    for (int k = 0; k < 4; k++) { Sx2[k] = (f32x2){0.f, 0.f}; Tx2[k] = (f32x2){0.f, 0.f}; }

    // register double-buffer: B fragments + meta for the next t
    bf16x8 bh[2][2];
    float4 mjb[2];
    {
        int boff = (jbase + l15) * DIM + quad * 8;
        bh[0][0] = *(const bf16x8*)(hi + boff);
        bh[0][1] = *(const bf16x8*)(hi + boff + 32);
        mjb[0] = meta[jbase + l15];
    }

#pragma unroll
    for (int t = 0; t < 8; t++) {
        int cur = t & 1, nxt = cur ^ 1;
        if (t < 7) {                       // STATIC under full unroll
            int jgn = jbase + (t + 1) * 16 + l15;
            int boff = jgn * DIM + quad * 8;
            bh[nxt][0] = *(const bf16x8*)(hi + boff);
            bh[nxt][1] = *(const bf16x8*)(hi + boff + 32);
            mjb[nxt] = meta[jgn];
        }
        float4 mj = mjb[cur];    // {hsqj, rcpomj, m4rj, labj}

        f32x2 sSum = (f32x2){0.f, 0.f}, tSum = (f32x2){0.f, 0.f};
#pragma unroll
        for (int it = 0; it < 2; it++) {
            f32x4 acc = hsqi4[it] + mj.x;          // norms folded via C operand
            acc = __builtin_amdgcn_mfma_f32_16x16x32_bf16(a_hi[it][0], bh[cur][0], acc, 0, 0, 0);
            acc = __builtin_amdgcn_mfma_f32_16x16x32_bf16(a_hi[it][1], bh[cur][1], acc, 0, 0, 0);

#pragma unroll
            for (int g = 0; g < 2; g++) {          // packed pairs (rows 2g, 2g+1)
                f32x2 D = (f32x2){acc[2 * g], acc[2 * g + 1]};
                f32x2 u = (D * rcp2[it * 2 + g]) * mj.z;
                u = __builtin_elementwise_max(u, (f32x2){EPSF, EPSF});
                f32x2 arg = u * u + (u + u);
                f32x2 srt = (f32x2){__builtin_amdgcn_sqrtf(arg.x), __builtin_amdgcn_sqrtf(arg.y)};
                f32x2 opu = u + 1.0f;
                f32x2 st = opu - srt;              // exp(-d)
                f32x2 w1 = opu + srt;              // exp(+d)
                f32x2 l2;
                l2.x = __builtin_amdgcn_logf(w1.x);
                l2.y = __builtin_amdgcn_logf(w1.y);
                f32x2 tv;
                tv.x = (mj.w == labi[it * 4 + 2 * g]) ? l2.x : 0.0f;
                tv.y = (mj.w == labi[it * 4 + 2 * g + 1]) ? l2.y : 0.0f;
                Sx2[it * 2 + g] += st;
                Tx2[it * 2 + g] += tv;
                sSum += st;
                tSum += tv;
            }
        }

        if (full) {
            float pS = sSum.x + sSum.y, pT = tSum.x + tSum.y;
            pS += __shfl_xor(pS, 16); pS += __shfl_xor(pS, 32);
            pT += __shfl_xor(pT, 16); pT += __shfl_xor(pT, 32);
            if (quad == 0) {
                int c = t * 16 + l15;
                slabS[wave][c] += pS;
                slabT[wave][c] += pT;
            }
        }
    }

    // i-side: unpack and reduce across the 16 j-columns
    float Sx[8], Tx[8];
#pragma unroll
    for (int k = 0; k < 4; k++) {
        Sx[2 * k] = Sx2[k].x; Sx[2 * k + 1] = Sx2[k].y;
        Tx[2 * k] = Tx2[k].x; Tx[2 * k + 1] = Tx2[k].y;
    }
#pragma unroll
    for (int r = 0; r < 8; r++) {
#pragma unroll
        for (int m = 1; m < 16; m <<= 1) {
            Sx[r] += __shfl_xor(Sx[r], m);
            Tx[r] += __shfl_xor(Tx[r], m);
        }
    }
    // plain stores to this block's private partial slice: [bid2][S:128 | T:128]
    float* PiB = Pi + (size_t)bid2 * 256;
    if (l15 == 0) {
#pragma unroll
        for (int it = 0; it < 2; it++)
#pragma unroll
            for (int r = 0; r < 4; r++) {
                int rowb = wave * 32 + it * 16 + quad * 4 + r;
                PiB[rowb] = Sx[it * 4 + r];
                PiB[128 + rowb] = Tx[it * 4 + r];
            }
    }

    // j-side: combine wave slabs, coalesced store (full tiles only)
    if (full) {
        __syncthreads();
        float* PjB = Pj + (size_t)bid2 * 256;
        if (tid < 128) {
            PjB[tid] = slabS[0][tid] + slabS[1][tid] + slabS[2][tid] + slabS[3][tid];
        } else {
            int c = tid - 128;
            PjB[tid] = slabT[0][c] + slabT[1][c] + slabT[2][c] + slabT[3][c];
        }
    }
}

// ---- kernel 3: gather partials + finalize, 128 blocks x 64 points x 4 slices
__global__ void __launch_bounds__(256) finalize_kernel(
        const float* __restrict__ Pi, const float* __restrict__ Pj,
        const int* __restrict__ labels, float* __restrict__ out) {
    __shared__ int hist[16][16];
    __shared__ float cntf[16];
    __shared__ float redS[4][64], redT[4][64];
    int tid = threadIdx.x;
    hist[tid >> 4][tid & 15] = 0;
    __syncthreads();
    int rep = tid & 15;
    for (int i = tid; i < NPTS; i += 256)
        atomicAdd(&hist[rep][labels[i]], 1);
    __syncthreads();
    if (tid < 16) {
        int s = 0;
#pragma unroll
        for (int k = 0; k < 16; k++) s += hist[k][tid];
        cntf[tid] = (float)(s - 1);
    }

    int slice = tid >> 6, pl = tid & 63;
    int i = blockIdx.x * 64 + pl;
    int bx = i >> 7, r = i & 127;
    float s = 0.f, t = 0.f;
    // i-side: blocks (by, off=bx-2by, half 0/1) for by in [0, bx/2]
    for (int by = slice; by <= (bx >> 1); by += 4) {
        int c2 = (cumtiles(by) + (bx - 2 * by)) * 512;   // bid2=2*bid -> *256 floats
        s += Pi[c2 + r] + Pi[c2 + 256 + r];
        t += Pi[c2 + 128 + r] + Pi[c2 + 384 + r];
    }
    // j-side: full blocks (byj, off in [2, 64-2byj), half = bx&1)
    int byj = bx >> 1, half = bx & 1;
    int jmax = 64 - 2 * byj;
    int cbase = cumtiles(byj);
    for (int off = 2 + slice; off < jmax; off += 4) {
        int c2 = ((cbase + off) * 2 + half) * 256;
        s += Pj[c2 + r];
        t += Pj[c2 + 128 + r];
    }
    redS[slice][pl] = s;
    redT[slice][pl] = t;
    __syncthreads();
    if (tid < 64) {
        float S = redS[0][tid] + redS[1][tid] + redS[2][tid] + redS[3][tid];
        float T = redT[0][tid] + redT[1][tid] + redT[2][tid] + redT[3][tid];
        float s0 = __builtin_amdgcn_sqrtf(EPSF * (2.0f + EPSF));
        float st0 = 1.0f + EPSF - s0;                         // self exp(-d) term
        float l20 = __builtin_amdgcn_logf(1.0f + EPSF + s0);  // self log2 term
        int ii = blockIdx.x * 64 + tid;
        float loss = __logf(S - st0) + (T - l20) * LN2F / cntf[labels[ii]];
#pragma unroll
        for (int m = 1; m < 64; m <<= 1) loss += __shfl_xor(loss, m);
        if (tid == 0) atomicAdd(out, loss);
    }
}

extern "C" void kernel_launch(void* const* d_in, const int* in_sizes, int n_in,
                              void* d_out, int out_size, void* d_ws, size_t ws_size,
                              hipStream_t stream) {
    const float* x = (const float*)d_in[0];
    const int* labels = (const int*)d_in[1];

    u16* hi = (u16*)d_ws;                 // NPTS*DIM u16 (1 MB)
    float4* meta = (float4*)(hi + NPTS * DIM);            // 128 KB
    float* Pi = (float*)(meta + NPTS);                    // 2112*256 floats (2.1 MB)
    float* Pj = Pi + 2 * NBLK * 256;                      // 2112*256 floats (2.1 MB)

    prep_kernel<<<(NPTS * 8) / 256, 256, 0, stream>>>(x, labels, hi, meta, (float*)d_out);

    pair_mfma<<<2 * NBLK, 256, 0, stream>>>(hi, meta, Pi, Pj);

    finalize_kernel<<<NPTS / 64, 256, 0, stream>>>(Pi, Pj, labels, (float*)d_out);
}

// Round 8
// 102.637 us; speedup vs baseline: 1.2395x; 1.2395x over previous
//
#include <hip/hip_runtime.h>

#define NPTS 8192
#define DIM 64
#define EPSF 1e-7f
#define LN2F 0.69314718055994531f
#define NBLK 1056      // sum_{by=0}^{31} (64 - 2*by)

typedef unsigned short u16;
typedef __attribute__((ext_vector_type(8))) short bf16x8;   // 8 bf16 (4 VGPRs)
typedef __attribute__((ext_vector_type(8))) unsigned short u16x8;
typedef __attribute__((ext_vector_type(4))) float f32x4;
typedef __attribute__((ext_vector_type(2))) float f32x2;

// ---- kernel 1: x -> bf16 (round-to-nearest); meta = {-sq/2, 1/(1-sq), -4/(1-sq), label}
// Also zeroes S, T, out.
__global__ void prep_kernel(const float* __restrict__ x, const int* __restrict__ labels,
                            u16* __restrict__ hi,
                            float4* __restrict__ meta,
                            float* __restrict__ S, float* __restrict__ T,
                            float* __restrict__ out) {
    int g = blockIdx.x * blockDim.x + threadIdx.x;   // 0 .. NPTS*8-1
    int row = g >> 3, sub = g & 7;
    const float* xp = x + row * DIM + sub * 8;
    float v[8];
    float s = 0.f;
#pragma unroll
    for (int k = 0; k < 8; k++) { v[k] = xp[k]; s = fmaf(v[k], v[k], s); }
    s += __shfl_xor(s, 1);
    s += __shfl_xor(s, 2);
    s += __shfl_xor(s, 4);
    u16x8 h;
#pragma unroll
    for (int k = 0; k < 8; k++) {
        unsigned int bits = __float_as_uint(v[k]);
        unsigned int r = bits + 0x7FFFu + ((bits >> 16) & 1u);   // RTN-even bf16
        h[k] = (u16)(r >> 16);
    }
    *(u16x8*)(hi + row * DIM + sub * 8) = h;
    if (sub == 0) {
        float r = 1.0f / (1.0f - s);
        meta[row] = make_float4(-0.5f * s, r, -4.0f * r, (float)labels[row]);
    } else if (sub == 1) {
        S[row] = 0.f;
    } else if (sub == 2) {
        T[row] = 0.f;
    }
    if (g == 3) out[0] = 0.f;
}

// C(b) = number of active tiles with by < b
__device__ __forceinline__ int cumtiles(int b) { return 65 * b - b * b; }

// ---- kernel 2: triangular fused MFMA Gram + hyperbolic epilogue -------------
// R25: BRANCHLESS PREFETCH, everything else = R19 champion (102.7us total).
// Theory: `if (t<7) load bh[nxt]` makes the outstanding-vmem count at the
// loop-top merge path-dependent (3 vs 0), forcing the compiler to emit
// s_waitcnt vmcnt(0) before the bh[cur] consumers -> drains the just-issued
// t+1 prefetch -> full L2 round trip exposed every iteration. R24 tried to
// fix this via full unroll and died of register pressure (VGPR clamp 64 +
// scratch spill, WRITE 118MB). This version clamps the prefetch index
// instead (tn = min(t+1,7)): loads become unconditional -> vmcnt statically
// countable -> compiler can emit vmcnt(3) and leave the prefetch in flight.
// Redundant t=7 reload is L2-served and harmless. Register pressure
// IDENTICAL to champion.
__global__ void __launch_bounds__(256, 4) pair_mfma(
        const u16* __restrict__ hi,
        const float4* __restrict__ meta,
        float* __restrict__ Sarr, float* __restrict__ Tarr) {
    __shared__ float slabS[4][128], slabT[4][128];

    int tid = threadIdx.x;
    int wave = tid >> 6, lane = tid & 63;
    int quad = lane >> 4, l15 = lane & 15;

    // invert linear tile id -> (by, bx) in the triangular tile set
    int bid2 = blockIdx.x;
    int bid = bid2 >> 1;
    int half = bid2 & 1;
    int by = (int)((65.0f - __builtin_amdgcn_sqrtf(4225.0f - 4.0f * (float)bid)) * 0.5f);
    while (cumtiles(by + 1) <= bid) by++;
    while (cumtiles(by) > bid) by--;
    int off = bid - cumtiles(by);
    int bx = 2 * by + off;
    bool full = (off >= 2);

    int i0 = bx * 128 + wave * 32;
    int j0 = by * 256;
    int jbase = j0 + half * 128;     // this block's 8 j-groups start here

    bf16x8 a_hi[2][2];
#pragma unroll
    for (int it = 0; it < 2; it++)
#pragma unroll
        for (int ks = 0; ks < 2; ks++) {
            int aoff = (i0 + it * 16 + l15) * DIM + ks * 32 + quad * 8;
            a_hi[it][ks] = *(const bf16x8*)(hi + aoff);
        }

    f32x4 hsqi4[2];          // -sq_i/2 for this lane's 8 rows (C-init vector)
    f32x2 rcp2[4];           // 1/(1-sq_i) packed pairs
    float labi[8];
#pragma unroll
    for (int it = 0; it < 2; it++)
#pragma unroll
        for (int r = 0; r < 4; r++) {
            float4 m = meta[i0 + it * 16 + quad * 4 + r];
            hsqi4[it][r] = m.x;
            rcp2[it * 2 + (r >> 1)][r & 1] = m.y;
            labi[it * 4 + r] = m.w;
        }

    if (full) {
        slabS[wave][lane] = 0.f;       slabT[wave][lane] = 0.f;
        slabS[wave][lane + 64] = 0.f;  slabT[wave][lane + 64] = 0.f;
    }

    f32x2 Sx2[4], Tx2[4];
#pragma unroll
    for (int k = 0; k < 4; k++) { Sx2[k] = (f32x2){0.f, 0.f}; Tx2[k] = (f32x2){0.f, 0.f}; }

    // register double-buffer: B fragments + meta for the next t
    bf16x8 bh[2][2];
    float4 mjb[2];
    {
        int boff = (jbase + l15) * DIM + quad * 8;
        bh[0][0] = *(const bf16x8*)(hi + boff);
        bh[0][1] = *(const bf16x8*)(hi + boff + 32);
        mjb[0] = meta[jbase + l15];
    }

#pragma unroll 2
    for (int t = 0; t < 8; t++) {
        int cur = t & 1, nxt = cur ^ 1;
        {
            // BRANCHLESS prefetch: clamp index; t=7 issues a redundant
            // (L2-served, unconsumed) reload instead of a branch.
            int tn = (t < 7) ? (t + 1) : 7;
            int jgn = jbase + tn * 16 + l15;
            int boff = jgn * DIM + quad * 8;
            bh[nxt][0] = *(const bf16x8*)(hi + boff);
            bh[nxt][1] = *(const bf16x8*)(hi + boff + 32);
            mjb[nxt] = meta[jgn];
        }
        float4 mj = mjb[cur];    // {hsqj, rcpomj, m4rj, labj}

        f32x2 sSum = (f32x2){0.f, 0.f}, tSum = (f32x2){0.f, 0.f};
#pragma unroll
        for (int it = 0; it < 2; it++) {
            f32x4 acc = hsqi4[it] + mj.x;          // norms folded via C operand
            acc = __builtin_amdgcn_mfma_f32_16x16x32_bf16(a_hi[it][0], bh[cur][0], acc, 0, 0, 0);
            acc = __builtin_amdgcn_mfma_f32_16x16x32_bf16(a_hi[it][1], bh[cur][1], acc, 0, 0, 0);

#pragma unroll
            for (int g = 0; g < 2; g++) {          // packed pairs (rows 2g, 2g+1)
                f32x2 D = (f32x2){acc[2 * g], acc[2 * g + 1]};
                f32x2 u = (D * rcp2[it * 2 + g]) * mj.z;
                u = __builtin_elementwise_max(u, (f32x2){EPSF, EPSF});
                f32x2 arg = u * u + (u + u);
                f32x2 srt = (f32x2){__builtin_amdgcn_sqrtf(arg.x), __builtin_amdgcn_sqrtf(arg.y)};
                f32x2 opu = u + 1.0f;
                f32x2 st = opu - srt;              // exp(-d)
                f32x2 w1 = opu + srt;              // exp(+d)
                f32x2 l2;
                l2.x = __builtin_amdgcn_logf(w1.x);
                l2.y = __builtin_amdgcn_logf(w1.y);
                f32x2 tv;
                tv.x = (mj.w == labi[it * 4 + 2 * g]) ? l2.x : 0.0f;
                tv.y = (mj.w == labi[it * 4 + 2 * g + 1]) ? l2.y : 0.0f;
                Sx2[it * 2 + g] += st;
                Tx2[it * 2 + g] += tv;
                sSum += st;
                tSum += tv;
            }
        }

        if (full) {
            float pS = sSum.x + sSum.y, pT = tSum.x + tSum.y;
            pS += __shfl_xor(pS, 16); pS += __shfl_xor(pS, 32);
            pT += __shfl_xor(pT, 16); pT += __shfl_xor(pT, 32);
            if (quad == 0) {
                int c = t * 16 + l15;
                slabS[wave][c] += pS;
                slabT[wave][c] += pT;
            }
        }
    }

    // i-side: unpack and reduce across the 16 j-columns
    float Sx[8], Tx[8];
#pragma unroll
    for (int k = 0; k < 4; k++) {
        Sx[2 * k] = Sx2[k].x; Sx[2 * k + 1] = Sx2[k].y;
        Tx[2 * k] = Tx2[k].x; Tx[2 * k + 1] = Tx2[k].y;
    }
#pragma unroll
    for (int r = 0; r < 8; r++) {
#pragma unroll
        for (int m = 1; m < 16; m <<= 1) {
            Sx[r] += __shfl_xor(Sx[r], m);
            Tx[r] += __shfl_xor(Tx[r], m);
        }
    }
    if (l15 == 0) {
#pragma unroll
        for (int it = 0; it < 2; it++)
#pragma unroll
            for (int r = 0; r < 4; r++) {
                int row = i0 + it * 16 + quad * 4 + r;
                atomicAdd(&Sarr[row], Sx[it * 4 + r]);
                atomicAdd(&Tarr[row], Tx[it * 4 + r]);
            }
    }

    // j-side: flush per-wave slabs (full tiles only; block-uniform branch)
    if (full) {
        __syncthreads();
        if (tid < 128) {
            float s = slabS[0][tid] + slabS[1][tid] + slabS[2][tid] + slabS[3][tid];
            float tt = slabT[0][tid] + slabT[1][tid] + slabT[2][tid] + slabT[3][tid];
            atomicAdd(&Sarr[jbase + tid], s);
            atomicAdd(&Tarr[jbase + tid], tt);
        }
    }
}

// ---- kernel 3: finalize, 32 parallel blocks ---------------------------------
__global__ void __launch_bounds__(256) finalize_kernel(
        const float* __restrict__ S, const float* __restrict__ T,
        const int* __restrict__ labels, float* __restrict__ out) {
    __shared__ int hist[16][16];
    __shared__ float cntf[16];
    __shared__ float red[256];
    int tid = threadIdx.x;
    hist[tid >> 4][tid & 15] = 0;
    __syncthreads();
    int rep = tid & 15;
    for (int i = tid; i < NPTS; i += 256)
        atomicAdd(&hist[rep][labels[i]], 1);
    __syncthreads();
    if (tid < 16) {
        int s = 0;
#pragma unroll
        for (int k = 0; k < 16; k++) s += hist[k][tid];
        cntf[tid] = (float)(s - 1);
    }
    __syncthreads();

    float s0 = __builtin_amdgcn_sqrtf(EPSF * (2.0f + EPSF));
    float st0 = 1.0f + EPSF - s0;                         // self exp(-d) term
    float l20 = __builtin_amdgcn_logf(1.0f + EPSF + s0);  // self log2 term
    int i = blockIdx.x * 256 + tid;
    float loss = __logf(S[i] - st0) + (T[i] - l20) * LN2F / cntf[labels[i]];
    red[tid] = loss;
    __syncthreads();
    for (int s = 128; s > 0; s >>= 1) {
        if (tid < s) red[tid] += red[tid + s];
        __syncthreads();
    }
    if (tid == 0) atomicAdd(out, red[0]);
}

extern "C" void kernel_launch(void* const* d_in, const int* in_sizes, int n_in,
                              void* d_out, int out_size, void* d_ws, size_t ws_size,
                              hipStream_t stream) {
    const float* x = (const float*)d_in[0];
    const int* labels = (const int*)d_in[1];

    u16* hi = (u16*)d_ws;                 // NPTS*DIM u16
    float4* meta = (float4*)(hi + NPTS * DIM);
    float* S = (float*)(meta + NPTS);
    float* T = S + NPTS;

    prep_kernel<<<(NPTS * 8) / 256, 256, 0, stream>>>(x, labels, hi, meta, S, T, (float*)d_out);

    pair_mfma<<<2 * NBLK, 256, 0, stream>>>(hi, meta, S, T);

    finalize_kernel<<<NPTS / 256, 256, 0, stream>>>(S, T, labels, (float*)d_out);
}